// Round 1
// baseline (1815.559 us; speedup 1.0000x reference)
//
#include <hip/hip_runtime.h>
#include <hip/hip_bf16.h>
#include <stdint.h>

typedef __hip_bfloat16 bf16;
typedef __attribute__((ext_vector_type(8))) short v8s;   // 8 x bf16 (4 VGPR) MFMA frag
typedef __attribute__((ext_vector_type(4))) float v4f;   // MFMA accum

#define NPTS 32768
#define KTOT 2336      // TOTAL features
#define MPH  2368      // padded half-width (64*37) of the 4672-wide hidden

#define AS1C(p) ((const __attribute__((address_space(1))) void*)(p))
#define AS3(p)  ((__attribute__((address_space(3))) void*)(p))

__device__ __forceinline__ float sigm(float x){ return 1.0f/(1.0f + expf(-x)); }
__device__ __forceinline__ float gelu_tanh(float x){
  // jax.nn.gelu default approximate=True
  float u = 0.7978845608028654f*(x + 0.044715f*x*x*x);
  return 0.5f*x*(1.0f + tanhf(u));
}
__device__ __forceinline__ float bf2f(uint16_t h){
  union{uint32_t u; float f;} c; c.u = ((uint32_t)h)<<16; return c.f;
}

// ---------------------------------------------------------------- preamble MLP
__global__ __launch_bounds__(256) void k_preamble(
    const float* __restrict__ pos, const float* __restrict__ t,
    const float* __restrict__ sph_proj, const float* __restrict__ tb1,
    const float* __restrict__ tb2,
    const float* __restrict__ gn1, const float* __restrict__ gw1,
    const float* __restrict__ gn2, const float* __restrict__ gw2,
    const float* __restrict__ gn3, const float* __restrict__ gw3,
    float4* __restrict__ Pbuf)
{
  int i = blockIdx.x*256 + threadIdx.x;
  if(i >= NPTS) return;
  float px = pos[3*i], py = pos[3*i+1], pz = pos[3*i+2];
  float rho = sqrtf(px*px + py*py + pz*pz);
  float phi = atan2f(py, px);
  float cz = fminf(1.0f, fmaxf(-1.0f, pz/rho));
  float theta = acosf(cz);
  float tv = t[i];
  float h[12];
  #pragma unroll
  for(int j=0;j<8;j++)
    h[j] = rho*sph_proj[j] + phi*sph_proj[8+j] + theta*sph_proj[16+j];
  float ct = cosf(tv + tb1[0]);
  float st = sinf(tv + tb2[0]);
  h[8]=ct; h[9]=st; h[10]=ct*sigm(ct); h[11]=st*sigm(st);

  float ss = 0.f;
  #pragma unroll
  for(int j=0;j<12;j++) ss += h[j]*h[j];
  float den = sqrtf(ss/12.0f) + 1e-8f;
  float hn[12];
  #pragma unroll
  for(int j=0;j<12;j++) hn[j] = gn1[j]*h[j]/den;

  float h2[16];
  #pragma unroll
  for(int j=0;j<16;j++){
    float a=0.f, g=0.f;
    #pragma unroll
    for(int k=0;k<12;k++){ a += hn[k]*gw1[k*32+j]; g += hn[k]*gw1[k*32+16+j]; }
    h2[j] = a*gelu_tanh(g);
  }
  ss = 0.f;
  #pragma unroll
  for(int j=0;j<16;j++) ss += h2[j]*h2[j];
  den = sqrtf(ss/16.0f) + 1e-8f;
  float hn2[16];
  #pragma unroll
  for(int j=0;j<16;j++) hn2[j] = gn2[j]*h2[j]/den;

  float h3[16];
  #pragma unroll
  for(int j=0;j<16;j++){
    float a=0.f, g=0.f;
    #pragma unroll
    for(int k=0;k<16;k++){ a += hn2[k]*gw2[k*32+j]; g += hn2[k]*gw2[k*32+16+j]; }
    h3[j] = a*gelu_tanh(g);
  }
  ss = 0.f;
  #pragma unroll
  for(int j=0;j<16;j++) ss += h3[j]*h3[j];
  den = sqrtf(ss/16.0f) + 1e-8f;
  float q[3];
  #pragma unroll
  for(int j=0;j<3;j++){
    float a=0.f;
    #pragma unroll
    for(int k=0;k<16;k++) a += (gn3[k]*h3[k]/den)*gw3[k*3+j];
    q[j] = sigm(a);
  }
  Pbuf[i] = make_float4(q[0], q[1], q[2], tv);
}

// ---------------------------------------------------------------- table gather
__device__ __forceinline__ float row_copy(const float* __restrict__ rowp, int F,
                                          bf16* __restrict__ dst, int lane){
  float ss = 0.f;
  for(int f=lane; f<F; f+=64){
    float v = rowp[f];
    dst[f] = __float2bfloat16(v);
    ss += v*v;
  }
  return ss;
}

__device__ __forceinline__ float table3_gather(const float* __restrict__ T, int d, int F,
    float p0, float p1, float p2, bf16* __restrict__ dst, int lane){
  int ix = (int)(p0*(float)(d-1));
  int iy = (int)(p1*(float)(d-1));
  int iz = (int)(p2*(float)(d-1));
  int xp = (ix+1>=d)?0:ix+1, xm = (ix==0)?d-1:ix-1;
  int yp = (iy+1>=d)?0:iy+1, ym = (iy==0)?d-1:iy-1;
  int zp = (iz+1>=d)?0:iz+1, zm = (iz==0)?d-1:iz-1;
  float ss = 0.f;
  ss += row_copy(T + ((size_t)(ix*d+iy)*d+iz)*F, F, dst + 0*F, lane);
  ss += row_copy(T + ((size_t)(xp*d+iy)*d+iz)*F, F, dst + 1*F, lane);
  ss += row_copy(T + ((size_t)(xm*d+iy)*d+iz)*F, F, dst + 2*F, lane);
  ss += row_copy(T + ((size_t)(ix*d+yp)*d+iz)*F, F, dst + 3*F, lane);
  ss += row_copy(T + ((size_t)(ix*d+ym)*d+iz)*F, F, dst + 4*F, lane);
  ss += row_copy(T + ((size_t)(ix*d+iy)*d+zp)*F, F, dst + 5*F, lane);
  ss += row_copy(T + ((size_t)(ix*d+iy)*d+zm)*F, F, dst + 6*F, lane);
  return ss;
}

__device__ __forceinline__ float table4_gather(const float* __restrict__ T,
    int d0,int d1,int d2,int d3,int F,
    float p0,float p1,float p2,float p3, bf16* __restrict__ dst, int lane){
  int ix = (int)(p0*(float)(d0-1));
  int iy = (int)(p1*(float)(d1-1));
  int iz = (int)(p2*(float)(d2-1));
  int iw = (int)(p3*(float)(d3-1));
  int xp=(ix+1>=d0)?0:ix+1, xm=(ix==0)?d0-1:ix-1;
  int yp=(iy+1>=d1)?0:iy+1, ym=(iy==0)?d1-1:iy-1;
  int zp=(iz+1>=d2)?0:iz+1, zm=(iz==0)?d2-1:iz-1;
  int wp=(iw+1>=d3)?0:iw+1, wm=(iw==0)?d3-1:iw-1;
  float ss = 0.f;
  #define RP(x,y,z,w) (T + ((((size_t)(x)*d1 + (y))*d2 + (z))*d3 + (w))*F)
  ss += row_copy(RP(ix,iy,iz,iw), F, dst + 0*F, lane);
  ss += row_copy(RP(xp,iy,iz,iw), F, dst + 1*F, lane);
  ss += row_copy(RP(xm,iy,iz,iw), F, dst + 2*F, lane);
  ss += row_copy(RP(ix,yp,iz,iw), F, dst + 3*F, lane);
  ss += row_copy(RP(ix,ym,iz,iw), F, dst + 4*F, lane);
  ss += row_copy(RP(ix,iy,zp,iw), F, dst + 5*F, lane);
  ss += row_copy(RP(ix,iy,zm,iw), F, dst + 6*F, lane);
  ss += row_copy(RP(ix,iy,iz,wp), F, dst + 7*F, lane);
  ss += row_copy(RP(ix,iy,iz,wm), F, dst + 8*F, lane);
  #undef RP
  return ss;
}

__global__ __launch_bounds__(256) void k_gather(
    const float4* __restrict__ Pbuf,
    const float* __restrict__ T0, const float* __restrict__ T1,
    const float* __restrict__ T2, const float* __restrict__ T3,
    const float* __restrict__ S1, const float* __restrict__ S2,
    const float* __restrict__ TF,
    bf16* __restrict__ X, float* __restrict__ sx)
{
  int wave = threadIdx.x>>6, lane = threadIdx.x&63;
  int ptid = blockIdx.x*4 + wave;
  float4 P = Pbuf[ptid];
  bf16* dst = X + (size_t)ptid*KTOT;
  float ss = 0.f;
  ss += table3_gather(T0, 128, 16, P.x, P.y, P.z, dst + 0,    lane);
  ss += table3_gather(T1,  64, 32, P.x, P.y, P.z, dst + 112,  lane);
  ss += table3_gather(T2,  32, 64, P.x, P.y, P.z, dst + 336,  lane);
  ss += table3_gather(T3,  16,128, P.x, P.y, P.z, dst + 784,  lane);
  ss += table4_gather(S1, 16,16,16,64, 64, P.x,P.y,P.z,P.w, dst + 1680, lane);
  ss += table4_gather(S2, 64,64,32,16,  8, P.x,P.y,P.z,P.w, dst + 2256, lane);
  {
    int ix=(int)(P.x*3.0f), iy=(int)(P.y*3.0f), iz=(int)(P.z*3.0f);
    int iw=(int)(P.w*65535.0f);
    ss += row_copy(TF + (((size_t)((ix*4+iy)*4+iz))*65536 + iw)*8, 8, dst + 2328, lane);
  }
  #pragma unroll
  for(int o=32;o>0;o>>=1) ss += __shfl_xor(ss, o);
  if(lane==0) sx[ptid] = 1.0f/(sqrtf(ss/2336.0f) + 1e-8f);
}

// ------------------------------------------- W1 prep: transpose+scale+bf16+pad
// W1b layout: [2*MPH][KTOT] bf16, row m' = output column, vn1 folded in.
__global__ __launch_bounds__(256) void k_w1prep(const float* __restrict__ vw1,
                                                const float* __restrict__ vn1,
                                                bf16* __restrict__ W1b)
{
  __shared__ float tile[32][33];
  int h  = blockIdx.z;
  int m0 = blockIdx.x*32, k0 = blockIdx.y*32;
  int tx = threadIdx.x & 31, ty = threadIdx.x >> 5;   // 32 x 8
  #pragma unroll
  for(int dy=0; dy<32; dy+=8){
    int k = k0 + ty + dy;
    tile[ty+dy][tx] = vw1[(size_t)k*4672 + h*2336 + m0 + tx] * vn1[k];
  }
  __syncthreads();
  #pragma unroll
  for(int dy=0; dy<32; dy+=8){
    int m = m0 + ty + dy;
    W1b[(size_t)(h*MPH + m)*KTOT + k0 + tx] = __float2bfloat16(tile[tx][ty+dy]);
  }
}

__global__ __launch_bounds__(256) void k_w1pad(bf16* __restrict__ W1b){
  int idx = blockIdx.x*256 + threadIdx.x;
  const int total = 2*32*KTOT;
  if(idx >= total) return;
  int h = idx / (32*KTOT);
  int r = idx % (32*KTOT);
  int m = 2336 + r / KTOT;
  int k = r % KTOT;
  W1b[(size_t)(h*MPH + m)*KTOT + k] = __float2bfloat16(0.0f);
}

// ---------------------- W2f prep: vn2 (.) vw2 @ fw[0:64]  -> (2336 x 4) fp32
__global__ __launch_bounds__(256) void k_w2prep(const float* __restrict__ vw2,
                                                const float* __restrict__ vn2,
                                                const float* __restrict__ fw,
                                                float4* __restrict__ W2f)
{
  int k = blockIdx.x*256 + threadIdx.x;
  if(k >= KTOT) return;
  float a0=0,a1=0,a2=0,a3=0;
  for(int i=0;i<64;i++){
    float w = vw2[k*64+i];
    a0 += w*fw[i*4+0]; a1 += w*fw[i*4+1]; a2 += w*fw[i*4+2]; a3 += w*fw[i*4+3];
  }
  float s = vn2[k];
  W2f[k] = make_float4(s*a0, s*a1, s*a2, s*a3);
}

// ------------------------------------------------ GEMM-B + fused GeGLU epilogue
// V[row][col] = (sx*accA) * gelu(sx*accG), tiles: BM=128, BN=64 (x2 halves), BK=32
__global__ __launch_bounds__(256) void k_gemm1(
    const bf16* __restrict__ X, const bf16* __restrict__ W1b,
    const float* __restrict__ sx, bf16* __restrict__ V)
{
  __shared__ bf16 As[128*32];
  __shared__ bf16 Bs[2*64*32];
  int tid = threadIdx.x;
  int wave = tid>>6, lane = tid&63;
  int bx = blockIdx.x, by = blockIdx.y;
  int row0 = by*128;
  int colh = bx*64;
  int wm = wave>>1, wn = wave&1;
  int lm = lane&15, lq = lane>>4;

  v4f acc[2][4][2];
  #pragma unroll
  for(int h=0;h<2;h++)
    #pragma unroll
    for(int i=0;i<4;i++)
      #pragma unroll
      for(int j=0;j<2;j++)
        acc[h][i][j] = (v4f){0.f,0.f,0.f,0.f};

  const bf16* Xb  = X   + (size_t)row0*KTOT;
  const bf16* Wb0 = W1b + (size_t)colh*KTOT;
  const bf16* Wb1 = W1b + (size_t)(MPH + colh)*KTOT;

  for(int k0=0; k0<KTOT; k0+=32){
    #pragma unroll
    for(int it=0; it<2; it++){
      int c = it*256 + tid;                      // chunk id: (row, kchunk)
      const bf16* g = Xb + (size_t)(c>>2)*KTOT + k0 + (c&3)*8;
      __builtin_amdgcn_global_load_lds(AS1C(g), AS3(As + (size_t)(it*256 + wave*64)*8), 16, 0, 0);
    }
    {
      const bf16* g  = Wb0 + (size_t)(tid>>2)*KTOT + k0 + (tid&3)*8;
      __builtin_amdgcn_global_load_lds(AS1C(g),  AS3(Bs + (size_t)(wave*64)*8),       16, 0, 0);
      const bf16* g2 = Wb1 + (size_t)(tid>>2)*KTOT + k0 + (tid&3)*8;
      __builtin_amdgcn_global_load_lds(AS1C(g2), AS3(Bs + (size_t)(256 + wave*64)*8), 16, 0, 0);
    }
    __syncthreads();

    v8s af[4], ba[2], bg[2];
    #pragma unroll
    for(int i=0;i<4;i++){
      int r = wm*64 + i*16 + lm;
      af[i] = *(const v8s*)(As + (size_t)(r*4 + lq)*8);
    }
    #pragma unroll
    for(int j=0;j<2;j++){
      int r = wn*32 + j*16 + lm;
      ba[j] = *(const v8s*)(Bs + (size_t)(r*4 + lq)*8);
      bg[j] = *(const v8s*)(Bs + (size_t)(256*8) + (size_t)(r*4 + lq)*8);
    }
    #pragma unroll
    for(int i=0;i<4;i++)
      #pragma unroll
      for(int j=0;j<2;j++){
        acc[0][i][j] = __builtin_amdgcn_mfma_f32_16x16x32_bf16(af[i], ba[j], acc[0][i][j], 0,0,0);
        acc[1][i][j] = __builtin_amdgcn_mfma_f32_16x16x32_bf16(af[i], bg[j], acc[1][i][j], 0,0,0);
      }
    __syncthreads();
  }

  // epilogue: C/D frag mapping col=lane&15, row=(lane>>4)*4+reg
  #pragma unroll
  for(int i=0;i<4;i++){
    #pragma unroll
    for(int r=0;r<4;r++){
      int grow = row0 + wm*64 + i*16 + lq*4 + r;
      float s = sx[grow];
      #pragma unroll
      for(int j=0;j<2;j++){
        int gcol = colh + wn*32 + j*16 + lm;     // in padded half space
        float va = s*acc[0][i][j][r];
        float vg = s*acc[1][i][j][r];
        float v = va * gelu_tanh(vg);
        if(gcol < KTOT)
          V[(size_t)grow*KTOT + gcol] = __float2bfloat16(v);
      }
    }
  }
}

// ------------------------------------------------ row sumsq of V -> sv scale
__global__ __launch_bounds__(256) void k_rowred(const bf16* __restrict__ V,
                                                float* __restrict__ sv){
  int wave = threadIdx.x>>6, lane = threadIdx.x&63;
  int row = blockIdx.x*4 + wave;
  const uint32_t* Vu = (const uint32_t*)(V + (size_t)row*KTOT);
  float ss = 0.f;
  for(int idx=lane; idx<KTOT/2; idx+=64){
    uint32_t u = Vu[idx];
    float a = bf2f((uint16_t)(u & 0xffffu));
    float b = bf2f((uint16_t)(u >> 16));
    ss += a*a + b*b;
  }
  #pragma unroll
  for(int o=32;o>0;o>>=1) ss += __shfl_xor(ss, o);
  if(lane==0) sv[row] = 1.0f/(sqrtf(ss/2336.0f) + 1e-8f);
}

// ------------------------------- final: out = sv*(V@W2f) + [p,t]@fw[64:] + fb
__global__ __launch_bounds__(256) void k_final(const bf16* __restrict__ V,
    const float* __restrict__ sv, const float4* __restrict__ Pbuf,
    const float4* __restrict__ W2f, const float* __restrict__ fw,
    const float* __restrict__ fb, float4* __restrict__ out)
{
  int wave = threadIdx.x>>6, lane = threadIdx.x&63;
  int p = blockIdx.x*4 + wave;
  const uint32_t* Vu = (const uint32_t*)(V + (size_t)p*KTOT);
  float a0=0,a1=0,a2=0,a3=0;
  for(int idx=lane; idx<KTOT/2; idx+=64){
    uint32_t u = Vu[idx];
    float va = bf2f((uint16_t)(u & 0xffffu));
    float vb = bf2f((uint16_t)(u >> 16));
    float4 w0 = W2f[2*idx], w1 = W2f[2*idx+1];
    a0 += va*w0.x + vb*w1.x;
    a1 += va*w0.y + vb*w1.y;
    a2 += va*w0.z + vb*w1.z;
    a3 += va*w0.w + vb*w1.w;
  }
  #pragma unroll
  for(int o=32;o>0;o>>=1){
    a0 += __shfl_xor(a0,o); a1 += __shfl_xor(a1,o);
    a2 += __shfl_xor(a2,o); a3 += __shfl_xor(a3,o);
  }
  if(lane==0){
    float s = sv[p];
    float4 P = Pbuf[p];
    float o0 = s*a0 + P.x*fw[64*4+0] + P.y*fw[65*4+0] + P.z*fw[66*4+0] + P.w*fw[67*4+0] + fb[0];
    float o1 = s*a1 + P.x*fw[64*4+1] + P.y*fw[65*4+1] + P.z*fw[66*4+1] + P.w*fw[67*4+1] + fb[1];
    float o2 = s*a2 + P.x*fw[64*4+2] + P.y*fw[65*4+2] + P.z*fw[66*4+2] + P.w*fw[67*4+2] + fb[2];
    float o3 = s*a3 + P.x*fw[64*4+3] + P.y*fw[65*4+3] + P.z*fw[66*4+3] + P.w*fw[67*4+3] + fb[3];
    out[p] = make_float4(o0,o1,o2,o3);
  }
}

// ---------------------------------------------------------------------- launch
extern "C" void kernel_launch(void* const* d_in, const int* in_sizes, int n_in,
                              void* d_out, int out_size, void* d_ws, size_t ws_size,
                              hipStream_t stream)
{
  const float* pos = (const float*)d_in[0];
  const float* t   = (const float*)d_in[2];
  const float* T0  = (const float*)d_in[3];
  const float* T1  = (const float*)d_in[4];
  const float* T2  = (const float*)d_in[5];
  const float* T3  = (const float*)d_in[6];
  const float* S1  = (const float*)d_in[7];
  const float* S2  = (const float*)d_in[8];
  const float* TF  = (const float*)d_in[9];
  const float* sph = (const float*)d_in[10];
  const float* tb1 = (const float*)d_in[11];
  const float* tb2 = (const float*)d_in[12];
  const float* gn1 = (const float*)d_in[13];
  const float* gw1 = (const float*)d_in[14];
  const float* gn2 = (const float*)d_in[15];
  const float* gw2 = (const float*)d_in[16];
  const float* gn3 = (const float*)d_in[17];
  const float* gw3 = (const float*)d_in[18];
  const float* vn1 = (const float*)d_in[19];
  const float* vw1 = (const float*)d_in[20];
  const float* vn2 = (const float*)d_in[21];
  const float* vw2 = (const float*)d_in[22];
  const float* fw  = (const float*)d_in[23];
  const float* fb  = (const float*)d_in[24];

  uint8_t* ws = (uint8_t*)d_ws;
  size_t off = 0;
  auto carve = [&](size_t bytes)->void*{
    void* pp = ws + off; off += (bytes + 255) & ~(size_t)255; return pp;
  };
  float4* Pbuf = (float4*)carve((size_t)NPTS*sizeof(float4));
  float*  sx   = (float*) carve((size_t)NPTS*sizeof(float));
  float*  sv   = (float*) carve((size_t)NPTS*sizeof(float));
  float4* W2f  = (float4*)carve((size_t)KTOT*sizeof(float4));
  bf16*   W1b  = (bf16*)  carve((size_t)2*MPH*KTOT*sizeof(bf16));
  bf16*   X    = (bf16*)  carve((size_t)NPTS*KTOT*sizeof(bf16));
  bf16*   V    = (bf16*)  carve((size_t)NPTS*KTOT*sizeof(bf16));

  k_preamble<<<NPTS/256, 256, 0, stream>>>(pos, t, sph, tb1, tb2,
                                           gn1, gw1, gn2, gw2, gn3, gw3, Pbuf);
  k_gather<<<NPTS/4, 256, 0, stream>>>(Pbuf, T0, T1, T2, T3, S1, S2, TF, X, sx);
  k_w1prep<<<dim3(73,73,2), 256, 0, stream>>>(vw1, vn1, W1b);
  k_w1pad<<<(2*32*KTOT + 255)/256, 256, 0, stream>>>(W1b);
  k_w2prep<<<(KTOT + 255)/256, 256, 0, stream>>>(vw2, vn2, fw, W2f);
  k_gemm1<<<dim3(37, 256), 256, 0, stream>>>(X, W1b, sx, V);
  k_rowred<<<NPTS/4, 256, 0, stream>>>(V, sv);
  k_final<<<NPTS/4, 256, 0, stream>>>(V, sv, Pbuf, W2f, fw, fb, (float4*)d_out);
}

// Round 2
// 1790.507 us; speedup vs baseline: 1.0140x; 1.0140x over previous
//
#include <hip/hip_runtime.h>
#include <hip/hip_bf16.h>
#include <stdint.h>

typedef __hip_bfloat16 bf16;
typedef __attribute__((ext_vector_type(8))) short v8s;   // 8 x bf16 (4 VGPR) MFMA frag
typedef __attribute__((ext_vector_type(4))) float v4f;   // MFMA accum

#define NPTS 32768
#define KTOT 2336      // TOTAL features
#define MPH  2368      // padded half-width (64*37) of the 4672-wide hidden
#define NBX  37        // column tiles (MPH/64)

#define AS1C(p) ((const __attribute__((address_space(1))) void*)(p))
#define AS3(p)  ((__attribute__((address_space(3))) void*)(p))

__device__ __forceinline__ float sigm(float x){ return 1.0f/(1.0f + expf(-x)); }
__device__ __forceinline__ float gelu_tanh(float x){
  // precise form — used in preamble only (index-critical path, keep identical to R1)
  float u = 0.7978845608028654f*(x + 0.044715f*x*x*x);
  return 0.5f*x*(1.0f + tanhf(u));
}
__device__ __forceinline__ float gelu_fast(float x){
  // identical math: 0.5x(1+tanh(u)) == x*sigmoid(2u); __expf err ~1e-5 rel
  float u = 1.5957691216057308f*x*(1.0f + 0.044715f*x*x);
  return x / (1.0f + __expf(-u));
}

// ---------------------------------------------------------------- preamble MLP
__global__ __launch_bounds__(256) void k_preamble(
    const float* __restrict__ pos, const float* __restrict__ t,
    const float* __restrict__ sph_proj, const float* __restrict__ tb1,
    const float* __restrict__ tb2,
    const float* __restrict__ gn1, const float* __restrict__ gw1,
    const float* __restrict__ gn2, const float* __restrict__ gw2,
    const float* __restrict__ gn3, const float* __restrict__ gw3,
    float4* __restrict__ Pbuf)
{
  int i = blockIdx.x*256 + threadIdx.x;
  if(i >= NPTS) return;
  float px = pos[3*i], py = pos[3*i+1], pz = pos[3*i+2];
  float rho = sqrtf(px*px + py*py + pz*pz);
  float phi = atan2f(py, px);
  float cz = fminf(1.0f, fmaxf(-1.0f, pz/rho));
  float theta = acosf(cz);
  float tv = t[i];
  float h[12];
  #pragma unroll
  for(int j=0;j<8;j++)
    h[j] = rho*sph_proj[j] + phi*sph_proj[8+j] + theta*sph_proj[16+j];
  float ct = cosf(tv + tb1[0]);
  float st = sinf(tv + tb2[0]);
  h[8]=ct; h[9]=st; h[10]=ct*sigm(ct); h[11]=st*sigm(st);

  float ss = 0.f;
  #pragma unroll
  for(int j=0;j<12;j++) ss += h[j]*h[j];
  float den = sqrtf(ss/12.0f) + 1e-8f;
  float hn[12];
  #pragma unroll
  for(int j=0;j<12;j++) hn[j] = gn1[j]*h[j]/den;

  float h2[16];
  #pragma unroll
  for(int j=0;j<16;j++){
    float a=0.f, g=0.f;
    #pragma unroll
    for(int k=0;k<12;k++){ a += hn[k]*gw1[k*32+j]; g += hn[k]*gw1[k*32+16+j]; }
    h2[j] = a*gelu_tanh(g);
  }
  ss = 0.f;
  #pragma unroll
  for(int j=0;j<16;j++) ss += h2[j]*h2[j];
  den = sqrtf(ss/16.0f) + 1e-8f;
  float hn2[16];
  #pragma unroll
  for(int j=0;j<16;j++) hn2[j] = gn2[j]*h2[j]/den;

  float h3[16];
  #pragma unroll
  for(int j=0;j<16;j++){
    float a=0.f, g=0.f;
    #pragma unroll
    for(int k=0;k<16;k++){ a += hn2[k]*gw2[k*32+j]; g += hn2[k]*gw2[k*32+16+j]; }
    h3[j] = a*gelu_tanh(g);
  }
  ss = 0.f;
  #pragma unroll
  for(int j=0;j<16;j++) ss += h3[j]*h3[j];
  den = sqrtf(ss/16.0f) + 1e-8f;
  float q[3];
  #pragma unroll
  for(int j=0;j<3;j++){
    float a=0.f;
    #pragma unroll
    for(int k=0;k<16;k++) a += (gn3[k]*h3[k]/den)*gw3[k*3+j];
    q[j] = sigm(a);
  }
  Pbuf[i] = make_float4(q[0], q[1], q[2], tv);
}

// ---------------------------------------------------------------- table gather
// lane-packed row copy: for F<64, 64/F rows per pass (full lane utilization)
template<int F, int R>
__device__ __forceinline__ float rows_copyT(const float* __restrict__ T,
    const int (&offs)[R], bf16* __restrict__ dst, int lane){
  float ss = 0.f;
  if constexpr (F >= 64){
    #pragma unroll
    for(int r=0;r<R;r++){
      #pragma unroll
      for(int f0=0; f0<F; f0+=64){
        float v = T[(size_t)offs[r] + f0 + lane];
        dst[r*F + f0 + lane] = __float2bfloat16(v);
        ss += v*v;
      }
    }
  } else {
    constexpr int RPP = 64/F;
    int sub = lane / F;
    int f   = lane & (F-1);
    #pragma unroll
    for(int r0=0;r0<R;r0+=RPP){
      int r = r0 + sub;
      if(r < R){
        float v = T[(size_t)offs[r] + f];
        dst[r*F + f] = __float2bfloat16(v);
        ss += v*v;
      }
    }
  }
  return ss;
}

template<int F>
__device__ __forceinline__ float table3_gather(const float* __restrict__ T, int d,
    float p0, float p1, float p2, bf16* __restrict__ dst, int lane){
  int ix = (int)(p0*(float)(d-1));
  int iy = (int)(p1*(float)(d-1));
  int iz = (int)(p2*(float)(d-1));
  int xp = (ix+1>=d)?0:ix+1, xm = (ix==0)?d-1:ix-1;
  int yp = (iy+1>=d)?0:iy+1, ym = (iy==0)?d-1:iy-1;
  int zp = (iz+1>=d)?0:iz+1, zm = (iz==0)?d-1:iz-1;
  int offs[7] = {
    ((ix*d+iy)*d+iz)*F, ((xp*d+iy)*d+iz)*F, ((xm*d+iy)*d+iz)*F,
    ((ix*d+yp)*d+iz)*F, ((ix*d+ym)*d+iz)*F,
    ((ix*d+iy)*d+zp)*F, ((ix*d+iy)*d+zm)*F };
  return rows_copyT<F,7>(T, offs, dst, lane);
}

template<int F>
__device__ __forceinline__ float table4_gather(const float* __restrict__ T,
    int d0,int d1,int d2,int d3,
    float p0,float p1,float p2,float p3, bf16* __restrict__ dst, int lane){
  int ix = (int)(p0*(float)(d0-1));
  int iy = (int)(p1*(float)(d1-1));
  int iz = (int)(p2*(float)(d2-1));
  int iw = (int)(p3*(float)(d3-1));
  int xp=(ix+1>=d0)?0:ix+1, xm=(ix==0)?d0-1:ix-1;
  int yp=(iy+1>=d1)?0:iy+1, ym=(iy==0)?d1-1:iy-1;
  int zp=(iz+1>=d2)?0:iz+1, zm=(iz==0)?d2-1:iz-1;
  int wp=(iw+1>=d3)?0:iw+1, wm=(iw==0)?d3-1:iw-1;
  #define RO(x,y,z,w) (((((x)*d1 + (y))*d2 + (z))*d3 + (w))*F)
  int offs[9] = {
    RO(ix,iy,iz,iw), RO(xp,iy,iz,iw), RO(xm,iy,iz,iw),
    RO(ix,yp,iz,iw), RO(ix,ym,iz,iw), RO(ix,iy,zp,iw), RO(ix,iy,zm,iw),
    RO(ix,iy,iz,wp), RO(ix,iy,iz,wm) };
  #undef RO
  return rows_copyT<F,9>(T, offs, dst, lane);
}

__global__ __launch_bounds__(256) void k_gather(
    const float4* __restrict__ Pbuf,
    const float* __restrict__ T0, const float* __restrict__ T1,
    const float* __restrict__ T2, const float* __restrict__ T3,
    const float* __restrict__ S1, const float* __restrict__ S2,
    const float* __restrict__ TF,
    bf16* __restrict__ X, float* __restrict__ sx)
{
  int wave = threadIdx.x>>6, lane = threadIdx.x&63;
  int ptid = blockIdx.x*4 + wave;
  float4 P = Pbuf[ptid];
  bf16* dst = X + (size_t)ptid*KTOT;
  float ss = 0.f;
  ss += table3_gather<16 >(T0, 128, P.x, P.y, P.z, dst + 0,    lane);
  ss += table3_gather<32 >(T1,  64, P.x, P.y, P.z, dst + 112,  lane);
  ss += table3_gather<64 >(T2,  32, P.x, P.y, P.z, dst + 336,  lane);
  ss += table3_gather<128>(T3,  16, P.x, P.y, P.z, dst + 784,  lane);
  ss += table4_gather<64>(S1, 16,16,16,64, P.x,P.y,P.z,P.w, dst + 1680, lane);
  ss += table4_gather<8 >(S2, 64,64,32,16, P.x,P.y,P.z,P.w, dst + 2256, lane);
  {
    int ix=(int)(P.x*3.0f), iy=(int)(P.y*3.0f), iz=(int)(P.z*3.0f);
    int iw=(int)(P.w*65535.0f);
    int offs[1] = { (int)((((ix*4+iy)*4+iz))*65536 + iw)*8 };
    ss += rows_copyT<8,1>(TF, offs, dst + 2328, lane);
  }
  #pragma unroll
  for(int o=32;o>0;o>>=1) ss += __shfl_xor(ss, o);
  if(lane==0) sx[ptid] = 1.0f/(sqrtf(ss/2336.0f) + 1e-8f);
}

// ------------------------------------------- W1 prep: transpose+scale+bf16+pad
__global__ __launch_bounds__(256) void k_w1prep(const float* __restrict__ vw1,
                                                const float* __restrict__ vn1,
                                                bf16* __restrict__ W1b)
{
  __shared__ float tile[32][33];
  int h  = blockIdx.z;
  int m0 = blockIdx.x*32, k0 = blockIdx.y*32;
  int tx = threadIdx.x & 31, ty = threadIdx.x >> 5;   // 32 x 8
  #pragma unroll
  for(int dy=0; dy<32; dy+=8){
    int k = k0 + ty + dy;
    tile[ty+dy][tx] = vw1[(size_t)k*4672 + h*2336 + m0 + tx] * vn1[k];
  }
  __syncthreads();
  #pragma unroll
  for(int dy=0; dy<32; dy+=8){
    int m = m0 + ty + dy;
    W1b[(size_t)(h*MPH + m)*KTOT + k0 + tx] = __float2bfloat16(tile[tx][ty+dy]);
  }
}

__global__ __launch_bounds__(256) void k_w1pad(bf16* __restrict__ W1b){
  int idx = blockIdx.x*256 + threadIdx.x;
  const int total = 2*32*KTOT;
  if(idx >= total) return;
  int h = idx / (32*KTOT);
  int r = idx % (32*KTOT);
  int m = 2336 + r / KTOT;
  int k = r % KTOT;
  W1b[(size_t)(h*MPH + m)*KTOT + k] = __float2bfloat16(0.0f);
}

// ---------------------- W2f prep: vn2 (.) vw2 @ fw[0:64]  -> (2336 x 4) fp32
__global__ __launch_bounds__(256) void k_w2prep(const float* __restrict__ vw2,
                                                const float* __restrict__ vn2,
                                                const float* __restrict__ fw,
                                                float4* __restrict__ W2f)
{
  int k = blockIdx.x*256 + threadIdx.x;
  if(k >= KTOT) return;
  float a0=0,a1=0,a2=0,a3=0;
  for(int i=0;i<64;i++){
    float w = vw2[k*64+i];
    a0 += w*fw[i*4+0]; a1 += w*fw[i*4+1]; a2 += w*fw[i*4+2]; a3 += w*fw[i*4+3];
  }
  float s = vn2[k];
  W2f[k] = make_float4(s*a0, s*a1, s*a2, s*a3);
}

// -------------------- GEMM-B + fused GeGLU + W2f partial-reduction epilogue
// LDS chunk swizzle: logical (row,q) stored at physical slot row*4 + (q^((row>>1)&3))
// -> per 16-lane ds_read_b128 phase all 8 bank-groups hit, 2 lanes each (min).
__global__ __launch_bounds__(256) void k_gemm1(
    const bf16* __restrict__ X, const bf16* __restrict__ W1b,
    const float* __restrict__ sx, const float4* __restrict__ W2f,
    float* __restrict__ Part)
{
  __shared__ bf16 As[128*32];
  __shared__ bf16 Bs[2*64*32];
  int tid = threadIdx.x;
  int wave = tid>>6, lane = tid&63;
  int bx = blockIdx.x, by = blockIdx.y;
  int row0 = by*128;
  int colh = bx*64;
  int wm = wave>>1, wn = wave&1;
  int lm = lane&15, lq = lane>>4;

  v4f acc[2][4][2];
  #pragma unroll
  for(int h=0;h<2;h++)
    #pragma unroll
    for(int i=0;i<4;i++)
      #pragma unroll
      for(int j=0;j<2;j++)
        acc[h][i][j] = (v4f){0.f,0.f,0.f,0.f};

  const bf16* Xb  = X   + (size_t)row0*KTOT;
  const bf16* Wb0 = W1b + (size_t)colh*KTOT;
  const bf16* Wb1 = W1b + (size_t)(MPH + colh)*KTOT;

  // swizzled global chunk index for the lane's fixed physical LDS slot
  // A: slots c = it*256+tid ; B: slot tid (per half)
  int arow0 = (0*256+tid)>>2, aq0 = ((0*256+tid)&3) ^ (((0*256+tid)>>3)&3);
  int arow1 = (1*256+tid)>>2, aq1 = ((1*256+tid)&3) ^ (((1*256+tid)>>3)&3);
  int brow  = tid>>2,         bq  = (tid&3) ^ ((tid>>3)&3);

  // swizzled LDS read offsets (loop-invariant, element units of bf16)
  int aoff[4], boff[2];
  #pragma unroll
  for(int i=0;i<4;i++){
    int r = wm*64 + i*16 + lm;
    aoff[i] = (r*4 + (lq ^ ((r>>1)&3)))*8;
  }
  #pragma unroll
  for(int j=0;j<2;j++){
    int r = wn*32 + j*16 + lm;
    boff[j] = (r*4 + (lq ^ ((r>>1)&3)))*8;
  }

  for(int k0=0; k0<KTOT; k0+=32){
    {
      const bf16* g0 = Xb + (size_t)arow0*KTOT + k0 + aq0*8;
      __builtin_amdgcn_global_load_lds(AS1C(g0), AS3(As + (size_t)(wave*64)*8), 16, 0, 0);
      const bf16* g1 = Xb + (size_t)arow1*KTOT + k0 + aq1*8;
      __builtin_amdgcn_global_load_lds(AS1C(g1), AS3(As + (size_t)(256 + wave*64)*8), 16, 0, 0);
      const bf16* g2 = Wb0 + (size_t)brow*KTOT + k0 + bq*8;
      __builtin_amdgcn_global_load_lds(AS1C(g2), AS3(Bs + (size_t)(wave*64)*8), 16, 0, 0);
      const bf16* g3 = Wb1 + (size_t)brow*KTOT + k0 + bq*8;
      __builtin_amdgcn_global_load_lds(AS1C(g3), AS3(Bs + (size_t)(256 + wave*64)*8), 16, 0, 0);
    }
    __syncthreads();

    v8s af[4], ba[2], bg[2];
    #pragma unroll
    for(int i=0;i<4;i++) af[i] = *(const v8s*)(As + aoff[i]);
    #pragma unroll
    for(int j=0;j<2;j++){
      ba[j] = *(const v8s*)(Bs + boff[j]);
      bg[j] = *(const v8s*)(Bs + 2048 + boff[j]);
    }
    #pragma unroll
    for(int i=0;i<4;i++)
      #pragma unroll
      for(int j=0;j<2;j++){
        acc[0][i][j] = __builtin_amdgcn_mfma_f32_16x16x32_bf16(af[i], ba[j], acc[0][i][j], 0,0,0);
        acc[1][i][j] = __builtin_amdgcn_mfma_f32_16x16x32_bf16(af[i], bg[j], acc[1][i][j], 0,0,0);
      }
    __syncthreads();
  }

  // ---- epilogue: v = (sx*a)*gelu(sx*g); reduce v*W2f and v^2 per row ----
  // C/D frag mapping: col=lane&15, row=(lane>>4)*4+reg
  float* red = (float*)As;   // reuse LDS: 128 rows x 8 floats
  #pragma unroll
  for(int ph=0; ph<2; ph++){
    if(wn == ph){
      #pragma unroll
      for(int i=0;i<4;i++){
        #pragma unroll
        for(int r=0;r<4;r++){
          int lrow = wm*64 + i*16 + lq*4 + r;
          float s = sx[row0 + lrow];
          float d0=0,d1=0,d2=0,d3=0,ssq=0;
          #pragma unroll
          for(int j=0;j<2;j++){
            int gcol = colh + wn*32 + j*16 + lm;
            float va = s*acc[0][i][j][r];
            float vg = s*acc[1][i][j][r];
            float v  = va * gelu_fast(vg);       // v==0 on padded cols (W1b zero)
            int ci = gcol < KTOT ? gcol : KTOT-1;
            float4 w = W2f[ci];
            d0 += v*w.x; d1 += v*w.y; d2 += v*w.z; d3 += v*w.w;
            ssq += v*v;
          }
          #pragma unroll
          for(int o=1;o<16;o<<=1){
            d0 += __shfl_xor(d0,o); d1 += __shfl_xor(d1,o);
            d2 += __shfl_xor(d2,o); d3 += __shfl_xor(d3,o);
            ssq += __shfl_xor(ssq,o);
          }
          if(lm==0){
            if(ph==0){
              red[lrow*8+0]=d0; red[lrow*8+1]=d1; red[lrow*8+2]=d2;
              red[lrow*8+3]=d3; red[lrow*8+4]=ssq;
              red[lrow*8+5]=0.f; red[lrow*8+6]=0.f; red[lrow*8+7]=0.f;
            } else {
              red[lrow*8+0]+=d0; red[lrow*8+1]+=d1; red[lrow*8+2]+=d2;
              red[lrow*8+3]+=d3; red[lrow*8+4]+=ssq;
            }
          }
        }
      }
    }
    __syncthreads();
  }
  {
    int rr = tid >> 1, c4 = (tid & 1)*4;
    float4 val = *(float4*)&red[rr*8 + c4];
    *(float4*)&Part[((size_t)bx*NPTS + row0 + rr)*8 + c4] = val;
  }
}

// ---------------- finalize: sum partials, rmsnorm scalar, affine tail
__global__ __launch_bounds__(256) void k_finalize(const float* __restrict__ Part,
    const float4* __restrict__ Pbuf, const float* __restrict__ fw,
    const float* __restrict__ fb, float4* __restrict__ out)
{
  int row = blockIdx.x*256 + threadIdx.x;
  const float4* P4 = (const float4*)Part;
  float d0=0,d1=0,d2=0,d3=0,ss=0;
  for(int bx=0; bx<NBX; bx++){
    size_t base = ((size_t)bx*NPTS + row)*2;
    float4 a = P4[base];
    float4 b = P4[base+1];
    d0+=a.x; d1+=a.y; d2+=a.z; d3+=a.w; ss+=b.x;
  }
  float sv = 1.0f/(sqrtf(ss/2336.0f)+1e-8f);
  float4 P = Pbuf[row];
  float o0 = sv*d0 + P.x*fw[256+0] + P.y*fw[260+0] + P.z*fw[264+0] + P.w*fw[268+0] + fb[0];
  float o1 = sv*d1 + P.x*fw[256+1] + P.y*fw[260+1] + P.z*fw[264+1] + P.w*fw[268+1] + fb[1];
  float o2 = sv*d2 + P.x*fw[256+2] + P.y*fw[260+2] + P.z*fw[264+2] + P.w*fw[268+2] + fb[2];
  float o3 = sv*d3 + P.x*fw[256+3] + P.y*fw[260+3] + P.z*fw[264+3] + P.w*fw[268+3] + fb[3];
  out[row] = make_float4(o0,o1,o2,o3);
}

// ---------------------------------------------------------------------- launch
extern "C" void kernel_launch(void* const* d_in, const int* in_sizes, int n_in,
                              void* d_out, int out_size, void* d_ws, size_t ws_size,
                              hipStream_t stream)
{
  const float* pos = (const float*)d_in[0];
  const float* t   = (const float*)d_in[2];
  const float* T0  = (const float*)d_in[3];
  const float* T1  = (const float*)d_in[4];
  const float* T2  = (const float*)d_in[5];
  const float* T3  = (const float*)d_in[6];
  const float* S1  = (const float*)d_in[7];
  const float* S2  = (const float*)d_in[8];
  const float* TF  = (const float*)d_in[9];
  const float* sph = (const float*)d_in[10];
  const float* tb1 = (const float*)d_in[11];
  const float* tb2 = (const float*)d_in[12];
  const float* gn1 = (const float*)d_in[13];
  const float* gw1 = (const float*)d_in[14];
  const float* gn2 = (const float*)d_in[15];
  const float* gw2 = (const float*)d_in[16];
  const float* gn3 = (const float*)d_in[17];
  const float* gw3 = (const float*)d_in[18];
  const float* vn1 = (const float*)d_in[19];
  const float* vw1 = (const float*)d_in[20];
  const float* vn2 = (const float*)d_in[21];
  const float* vw2 = (const float*)d_in[22];
  const float* fw  = (const float*)d_in[23];
  const float* fb  = (const float*)d_in[24];

  uint8_t* ws = (uint8_t*)d_ws;
  size_t off = 0;
  auto carve = [&](size_t bytes)->void*{
    void* pp = ws + off; off += (bytes + 255) & ~(size_t)255; return pp;
  };
  float4* Pbuf = (float4*)carve((size_t)NPTS*sizeof(float4));
  float*  sx   = (float*) carve((size_t)NPTS*sizeof(float));
  float4* W2f  = (float4*)carve((size_t)KTOT*sizeof(float4));
  bf16*   W1b  = (bf16*)  carve((size_t)2*MPH*KTOT*sizeof(bf16));
  bf16*   X    = (bf16*)  carve((size_t)NPTS*KTOT*sizeof(bf16));
  float*  Part = (float*) carve((size_t)NBX*NPTS*8*sizeof(float));

  k_preamble<<<NPTS/256, 256, 0, stream>>>(pos, t, sph, tb1, tb2,
                                           gn1, gw1, gn2, gw2, gn3, gw3, Pbuf);
  k_gather<<<NPTS/4, 256, 0, stream>>>(Pbuf, T0, T1, T2, T3, S1, S2, TF, X, sx);
  k_w1prep<<<dim3(73,73,2), 256, 0, stream>>>(vw1, vn1, W1b);
  k_w1pad<<<(2*32*KTOT + 255)/256, 256, 0, stream>>>(W1b);
  k_w2prep<<<(KTOT + 255)/256, 256, 0, stream>>>(vw2, vn2, fw, W2f);
  k_gemm1<<<dim3(NBX, 256), 256, 0, stream>>>(X, W1b, sx, W2f, Part);
  k_finalize<<<NPTS/256, 256, 0, stream>>>(Part, Pbuf, fw, fb, (float4*)d_out);
}